// Round 4
// baseline (1812.561 us; speedup 1.0000x reference)
//
#include <hip/hip_runtime.h>
#include <hip/hip_bf16.h>

// ---------------- problem constants ----------------
#define NN 100000      // nodes
#define NE 800000      // edges
#define DIN 128
#define DCAT 384
#define BN_EPS 1e-5

typedef __attribute__((ext_vector_type(8))) short bf16x8;
typedef __attribute__((ext_vector_type(4))) float f32x4;
typedef __attribute__((ext_vector_type(4))) int   i32x4;

// ---------------- preprocessing kernels ----------------

__global__ void count_deg_k(const int* __restrict__ ei, int* __restrict__ deg) {
    int i = blockIdx.x * blockDim.x + threadIdx.x;
    if (i < NE) atomicAdd(&deg[ei[NE + i]], 1);   // col = ei[1][e]
}

__global__ void dinv_k(const int* __restrict__ deg, float* __restrict__ dinv) {
    int i = blockIdx.x * blockDim.x + threadIdx.x;
    if (i < NN) {
        int d = deg[i];
        dinv[i] = (d > 0) ? rsqrtf((float)d) : 0.f;
    }
}

__global__ void scan1_k(const int* __restrict__ deg, int* __restrict__ out,
                        int* __restrict__ bsum) {
    __shared__ int s[1024];
    int i = blockIdx.x * 1024 + threadIdx.x;
    int v = (i < NN) ? deg[i] : 0;
    s[threadIdx.x] = v;
    __syncthreads();
    for (int off = 1; off < 1024; off <<= 1) {
        int t = (threadIdx.x >= off) ? s[threadIdx.x - off] : 0;
        __syncthreads();
        s[threadIdx.x] += t;
        __syncthreads();
    }
    if (i < NN) out[i] = s[threadIdx.x] - v;   // exclusive
    if (threadIdx.x == 1023) bsum[blockIdx.x] = s[1023];
}

__global__ void scan2_k(int* __restrict__ bsum, int nb) {
    if (threadIdx.x == 0) {
        int acc = 0;
        for (int b = 0; b < nb; ++b) { int v = bsum[b]; bsum[b] = acc; acc += v; }
    }
}

__global__ void scan3_k(int* __restrict__ ptr, int* __restrict__ cursor,
                        const int* __restrict__ bsum) {
    int i = blockIdx.x * 1024 + threadIdx.x;
    if (i < NN) {
        int p = ptr[i] + bsum[blockIdx.x];
        ptr[i] = p;
        cursor[i] = p;
    }
    if (i == NN) ptr[NN] = NE;
}

__global__ void scatter_k(const int* __restrict__ ei, const float* __restrict__ dinv,
                          int* __restrict__ cursor, int* __restrict__ crow,
                          float* __restrict__ cw) {
    int i = blockIdx.x * blockDim.x + threadIdx.x;
    if (i >= NE) return;
    int r = ei[i];
    int c = ei[NE + i];
    int p = atomicAdd(&cursor[c], 1);
    crow[p] = r;
    cw[p] = dinv[r] * dinv[c];
}

// ---------------- split-bf16 helpers ----------------

__device__ inline void split_trunc(float x, short& hi, short& lo) {
    unsigned u = __builtin_bit_cast(unsigned, x);
    hi = (short)(u >> 16);
    float hf = __builtin_bit_cast(float, u & 0xFFFF0000u);
    __hip_bfloat16 l = __float2bfloat16(x - hf);
    lo = *reinterpret_cast<short*>(&l);
}

// pre-split + transpose weights:  W (3,K,128) -> Wt_hi/lo (3,128,384) [group][col][k]
__global__ void wsplit_k(const float* __restrict__ W, int K,
                         short* __restrict__ Wth, short* __restrict__ Wtl) {
    int i = blockIdx.x * 256 + threadIdx.x;
    if (i >= 3 * K * 128) return;
    int c = i & 127;
    int k = (i >> 7) % K;
    int j = i / (K * 128);
    short h, l;
    split_trunc(W[i], h, l);
    size_t o = (size_t)j * 128 * 384 + (size_t)c * 384 + k;
    Wth[o] = h;
    Wtl[o] = l;
}

// ---------------- BN(optional)+ReLU + split X into bf16 hi/lo ----------------
__global__ __launch_bounds__(256) void bnsplit_k(
    const float* __restrict__ H, int Kc4,   // Kc4 = K/4
    const float2* __restrict__ coef, int use_bn,
    short* __restrict__ Xh, short* __restrict__ Xl) {
    size_t n4 = (size_t)NN * Kc4;
    for (size_t i = (size_t)blockIdx.x * blockDim.x + threadIdx.x; i < n4;
         i += (size_t)gridDim.x * blockDim.x) {
        float4 v = ((const float4*)H)[i];
        if (use_bn) {
            int c4 = (int)(i % Kc4) * 4;
            float2 c0 = coef[c4 + 0], c1 = coef[c4 + 1];
            float2 c2 = coef[c4 + 2], c3 = coef[c4 + 3];
            v.x = fmaxf(v.x * c0.x + c0.y, 0.f);
            v.y = fmaxf(v.y * c1.x + c1.y, 0.f);
            v.z = fmaxf(v.z * c2.x + c2.y, 0.f);
            v.w = fmaxf(v.w * c3.x + c3.y, 0.f);
        }
        short h0, l0, h1, l1, h2, l2, h3, l3;
        split_trunc(v.x, h0, l0);
        split_trunc(v.y, h1, l1);
        split_trunc(v.z, h2, l2);
        split_trunc(v.w, h3, l3);
        ((short4*)Xh)[i] = make_short4(h0, h1, h2, h3);
        ((short4*)Xl)[i] = make_short4(l0, l1, l2, l3);
    }
}

// ---------------- pipelined split-bf16 MFMA GEMM ----------------
// A (Xh/Xl bf16, pitch K) double-buffered in LDS; B frags loaded global->reg
// (L2-resident weights); one barrier per K-step; XCD-chunked block swizzle.
#define GPITCH 40

__global__ __launch_bounds__(256, 3) void gemm3m_k(
    const short* __restrict__ Xh, const short* __restrict__ Xl, int K,
    const short* __restrict__ Wth, const short* __restrict__ Wtl,
    const float* __restrict__ bias,
    float* __restrict__ o0, int p0,
    float* __restrict__ o1, int p1,
    float* __restrict__ o2, int p2) {
    __shared__ short Ah[2][128 * GPITCH];
    __shared__ short Al[2][128 * GPITCH];

    // bijective XCD-chunked swizzle
    const int nwg = gridDim.x;
    const int id  = blockIdx.x;
    const int q = nwg >> 3, r = nwg & 7;
    const int xcd = id & 7, ii = id >> 3;
    const int swz = (xcd < r ? xcd * (q + 1) : r * (q + 1) + (xcd - r) * q) + ii;
    const int j  = swz % 3;
    const int m0 = (swz / 3) * 128;

    const int t    = threadIdx.x;
    const int lane = t & 63;
    const int wv   = t >> 6;
    const int wr   = (wv >> 1) * 64;
    const int wc   = (wv & 1) * 64;
    const int lr   = lane & 15;
    const int lk   = lane >> 4;

    const short* Wh = Wth + (size_t)j * 128 * 384;
    const short* Wl = Wtl + (size_t)j * 128 * 384;

    // A staging assignment: thread covers row = t>>1, 16 shorts at kc=(t&1)*16
    const int arow = t >> 1;
    const int akc  = (t & 1) * 16;
    int gr = m0 + arow;
    if (gr >= NN) gr = NN - 1;
    const short* pAh = Xh + (size_t)gr * K + akc;
    const short* pAl = Xl + (size_t)gr * K + akc;
    const int soff = arow * GPITCH + akc;

    f32x4 acc[4][4];
#pragma unroll
    for (int a = 0; a < 4; ++a)
#pragma unroll
        for (int b = 0; b < 4; ++b) acc[a][b] = (f32x4){0.f, 0.f, 0.f, 0.f};

    const int NT = K >> 5;   // K/32 steps

    // prologue: stage step 0
    {
        i32x4 h0 = *(const i32x4*)(pAh);
        i32x4 h1 = *(const i32x4*)(pAh + 8);
        i32x4 l0 = *(const i32x4*)(pAl);
        i32x4 l1 = *(const i32x4*)(pAl + 8);
        *(i32x4*)&Ah[0][soff]     = h0;
        *(i32x4*)&Ah[0][soff + 8] = h1;
        *(i32x4*)&Al[0][soff]     = l0;
        *(i32x4*)&Al[0][soff + 8] = l1;
    }
    __syncthreads();

    int cur = 0;
    for (int tt = 0; tt < NT; ++tt) {
        const int kb = tt << 5;

        // B fragments for this step: direct global->reg (L2-hot)
        bf16x8 bh[4], bl[4];
#pragma unroll
        for (int nc = 0; nc < 4; ++nc) {
            const size_t bo = (size_t)(wc + nc * 16 + lr) * 384 + kb + lk * 8;
            bh[nc] = *(const bf16x8*)(Wh + bo);
            bl[nc] = *(const bf16x8*)(Wl + bo);
        }

        // prefetch next A step into regs
        i32x4 h0, h1, l0, l1;
        if (tt + 1 < NT) {
            const int ko = kb + 32;
            h0 = *(const i32x4*)(pAh + ko);
            h1 = *(const i32x4*)(pAh + ko + 8);
            l0 = *(const i32x4*)(pAl + ko);
            l1 = *(const i32x4*)(pAl + ko + 8);
        }

        // A fragments from LDS[cur]
        bf16x8 ah[4], al[4];
#pragma unroll
        for (int mr = 0; mr < 4; ++mr) {
            const int rr = (wr + mr * 16 + lr) * GPITCH + lk * 8;
            ah[mr] = *(const bf16x8*)&Ah[cur][rr];
            al[mr] = *(const bf16x8*)&Al[cur][rr];
        }

#pragma unroll
        for (int nc = 0; nc < 4; ++nc) {
#pragma unroll
            for (int mr = 0; mr < 4; ++mr) {
                f32x4 a = acc[mr][nc];
                a = __builtin_amdgcn_mfma_f32_16x16x32_bf16(al[mr], bh[nc], a, 0, 0, 0);
                a = __builtin_amdgcn_mfma_f32_16x16x32_bf16(ah[mr], bl[nc], a, 0, 0, 0);
                a = __builtin_amdgcn_mfma_f32_16x16x32_bf16(ah[mr], bh[nc], a, 0, 0, 0);
                acc[mr][nc] = a;
            }
        }

        if (tt + 1 < NT) {
            const int nb = cur ^ 1;
            *(i32x4*)&Ah[nb][soff]     = h0;
            *(i32x4*)&Ah[nb][soff + 8] = h1;
            *(i32x4*)&Al[nb][soff]     = l0;
            *(i32x4*)&Al[nb][soff + 8] = l1;
        }
        __syncthreads();
        cur ^= 1;
    }

    float* dst;
    int pitch;
    if (j == 0)      { dst = o0; pitch = p0; }
    else if (j == 1) { dst = o1; pitch = p1; }
    else             { dst = o2; pitch = p2; }

#pragma unroll
    for (int nc = 0; nc < 4; ++nc) {
        int col = wc + nc * 16 + lr;
        float bv = bias[j * 128 + col];
#pragma unroll
        for (int mr = 0; mr < 4; ++mr) {
            f32x4 a = acc[mr][nc];
#pragma unroll
            for (int rr = 0; rr < 4; ++rr) {
                int row = m0 + wr + mr * 16 + lk * 4 + rr;
                if (row < NN) dst[(size_t)row * pitch + col] = a[rr] + bv;
            }
        }
    }
}

// ---------------- fused dual SpMM over interleaved [T1|T2] (pitch 256) ----------------
// Per edge: one 1024B float4 gather. lanes 0-31 accumulate T1, 32-63 T2.
__global__ __launch_bounds__(256) void spmm2_k(
    const int* __restrict__ ptr, const int* __restrict__ rows,
    const float* __restrict__ wv,
    const float* __restrict__ inAB,     // pitch 256
    float* __restrict__ outA,           // H + 128 (pitch 384)
    float* __restrict__ outB) {         // tmpC (pitch 128)
    int wid  = (blockIdx.x * blockDim.x + threadIdx.x) >> 6;
    int lane = threadIdx.x & 63;
    if (wid >= NN) return;
    int e0 = ptr[wid], e1 = ptr[wid + 1];
    float4 acc = make_float4(0.f, 0.f, 0.f, 0.f);
    int e = e0;
    for (; e + 2 <= e1; e += 2) {
        int   r0 = rows[e],  r1 = rows[e + 1];
        float w0 = wv[e],    w1 = wv[e + 1];
        float4 v0 = ((const float4*)(inAB + (size_t)r0 * 256))[lane];
        float4 v1 = ((const float4*)(inAB + (size_t)r1 * 256))[lane];
        acc.x += w0 * v0.x + w1 * v1.x;
        acc.y += w0 * v0.y + w1 * v1.y;
        acc.z += w0 * v0.z + w1 * v1.z;
        acc.w += w0 * v0.w + w1 * v1.w;
    }
    if (e < e1) {
        int   r0 = rows[e];
        float w0 = wv[e];
        float4 v0 = ((const float4*)(inAB + (size_t)r0 * 256))[lane];
        acc.x += w0 * v0.x;
        acc.y += w0 * v0.y;
        acc.z += w0 * v0.z;
        acc.w += w0 * v0.w;
    }
    if (lane < 32) ((float4*)(outA + (size_t)wid * 384))[lane] = acc;
    else           ((float4*)(outB + (size_t)wid * 128))[lane - 32] = acc;
}

// ---------------- single SpMM: 2 edges per wave (32 lanes each), float4 ----------------
__global__ __launch_bounds__(256) void spmm_k(
    const int* __restrict__ ptr, const int* __restrict__ rows,
    const float* __restrict__ wv,
    const float* __restrict__ xin,      // pitch 128
    float* __restrict__ xout, int pout) {
    int wid  = (blockIdx.x * blockDim.x + threadIdx.x) >> 6;
    int lane = threadIdx.x & 63;
    if (wid >= NN) return;
    int e0 = ptr[wid], e1 = ptr[wid + 1];
    int half = lane >> 5;
    int cl   = lane & 31;
    float4 acc = make_float4(0.f, 0.f, 0.f, 0.f);
    int e = e0;
    for (; e + 4 <= e1; e += 4) {
        int   ra = rows[e + half],     rb = rows[e + 2 + half];
        float wa = wv[e + half],       wb = wv[e + 2 + half];
        float4 va = ((const float4*)(xin + (size_t)ra * 128))[cl];
        float4 vb = ((const float4*)(xin + (size_t)rb * 128))[cl];
        acc.x += wa * va.x + wb * vb.x;
        acc.y += wa * va.y + wb * vb.y;
        acc.z += wa * va.z + wb * vb.z;
        acc.w += wa * va.w + wb * vb.w;
    }
    for (; e + 2 <= e1; e += 2) {
        int   ra = rows[e + half];
        float wa = wv[e + half];
        float4 va = ((const float4*)(xin + (size_t)ra * 128))[cl];
        acc.x += wa * va.x;
        acc.y += wa * va.y;
        acc.z += wa * va.z;
        acc.w += wa * va.w;
    }
    if (e < e1 && half == 0) {
        int   ra = rows[e];
        float wa = wv[e];
        float4 va = ((const float4*)(xin + (size_t)ra * 128))[cl];
        acc.x += wa * va.x;
        acc.y += wa * va.y;
        acc.z += wa * va.z;
        acc.w += wa * va.w;
    }
    float4 o;
    o.x = acc.x + __shfl_xor(acc.x, 32);
    o.y = acc.y + __shfl_xor(acc.y, 32);
    o.z = acc.z + __shfl_xor(acc.z, 32);
    o.w = acc.w + __shfl_xor(acc.w, 32);
    if (half == 0) ((float4*)(xout + (size_t)wid * pout))[cl] = o;
}

// ---------------- BatchNorm stats ----------------
#define BN_ROWS 256
#define BN_NBLK ((NN + BN_ROWS - 1) / BN_ROWS)   // 391

__global__ void bn_stats1_k(const float* __restrict__ H, float* __restrict__ partial) {
    int c  = threadIdx.x;                 // 384 threads
    int r0 = blockIdx.x * BN_ROWS;
    int r1 = min(r0 + BN_ROWS, NN);
    float s = 0.f, s2 = 0.f;
    for (int r = r0; r < r1; ++r) {
        float v = H[(size_t)r * DCAT + c];
        s  += v;
        s2 += v * v;
    }
    partial[blockIdx.x * 768 + c]       = s;
    partial[blockIdx.x * 768 + 384 + c] = s2;
}

__global__ void bn_finalize_k(const float* __restrict__ partial,
                              const float* __restrict__ g, const float* __restrict__ b,
                              float2* __restrict__ coef) {
    int c = threadIdx.x;                  // 384 threads
    double s = 0.0, s2 = 0.0;
    for (int i = 0; i < BN_NBLK; ++i) {
        s  += (double)partial[i * 768 + c];
        s2 += (double)partial[i * 768 + 384 + c];
    }
    double mu  = s / (double)NN;
    double var = s2 / (double)NN - mu * mu;
    double inv = 1.0 / sqrt(var + (double)BN_EPS);
    float scale = (float)((double)g[c] * inv);
    float shift = (float)((double)b[c] - mu * (double)g[c] * inv);
    coef[c] = make_float2(scale, shift);
}

// ---------------- host-side orchestration ----------------

static void run_layer(const short* Xh, const short* Xl, int K,
                      const float* W, const float* bias,
                      float* Hout, float* tmpAB, float* tmpC,
                      short* Wth, short* Wtl,
                      const int* ptr, const int* crow, const float* cw,
                      hipStream_t stream) {
    int nw = 3 * K * 128;
    wsplit_k<<<(nw + 255) / 256, 256, 0, stream>>>(W, K, Wth, Wtl);
    int nwg = 3 * ((NN + 127) / 128);
    gemm3m_k<<<nwg, 256, 0, stream>>>(Xh, Xl, K, Wth, Wtl, bias,
                                      Hout, DCAT, tmpAB, 256, tmpAB + 128, 256);
    int sg = (NN * 64 + 255) / 256;
    spmm2_k<<<sg, 256, 0, stream>>>(ptr, crow, cw, tmpAB, Hout + 128, tmpC);
    spmm_k<<<sg, 256, 0, stream>>>(ptr, crow, cw, tmpC, Hout + 256, DCAT);
}

extern "C" void kernel_launch(void* const* d_in, const int* in_sizes, int n_in,
                              void* d_out, int out_size, void* d_ws, size_t ws_size,
                              hipStream_t stream) {
    const float* x        = (const float*)d_in[0];
    const int*   ei       = (const int*)d_in[1];
    const float* W0       = (const float*)d_in[2];
    const float* b0       = (const float*)d_in[3];
    const float* W1       = (const float*)d_in[4];
    const float* b1       = (const float*)d_in[5];
    const float* W2       = (const float*)d_in[6];
    const float* b2       = (const float*)d_in[7];
    const float* bn_gamma = (const float*)d_in[8];
    const float* bn_beta  = (const float*)d_in[9];
    float* out = (float*)d_out;

    // workspace carve-up (512B aligned slabs)
    char* p = (char*)d_ws;
    auto alloc = [&](size_t bytes) -> void* {
        void* r = (void*)p;
        p += (bytes + 511) & ~(size_t)511;
        return r;
    };
    short* Xh      = (short*)alloc((size_t)NN * DCAT * 2);   // 76.8 MB
    short* Xl      = (short*)alloc((size_t)NN * DCAT * 2);   // 76.8 MB
    float* tmpAB   = (float*)alloc((size_t)NN * 256 * 4);    // 102.4 MB
    float* Hws     = (float*)alloc((size_t)NN * DCAT * 4);   // 153.6 MB
    int*   deg     = (int*)alloc((size_t)NN * 4);
    float* dinv    = (float*)alloc((size_t)NN * 4);
    int*   ptr     = (int*)alloc((size_t)(NN + 1) * 4);
    int*   cursor  = (int*)alloc((size_t)NN * 4);
    int*   bsum    = (int*)alloc(1024);
    int*   crow    = (int*)alloc((size_t)NE * 4);
    float* cw      = (float*)alloc((size_t)NE * 4);
    float* partial = (float*)alloc((size_t)BN_NBLK * 768 * 4);
    float2* coef   = (float2*)alloc(384 * 8);
    short* Wth     = (short*)alloc((size_t)3 * 128 * 384 * 2);
    short* Wtl     = (short*)alloc((size_t)3 * 128 * 384 * 2);
    // tmpC (N x 128 fp32, 51.2 MB) aliases Xh: X of the current layer is dead
    // once its gemm finished, and bnsplit of the next layer rewrites Xh after
    // spmm consumed tmpC (strictly sequential stream).
    float* tmpC = (float*)Xh;

    // ---- graph preprocessing ----
    hipMemsetAsync(deg, 0, (size_t)NN * 4, stream);
    count_deg_k<<<(NE + 255) / 256, 256, 0, stream>>>(ei, deg);
    dinv_k<<<(NN + 255) / 256, 256, 0, stream>>>(deg, dinv);
    int nsb = (NN + 1023) / 1024;   // 98
    scan1_k<<<nsb, 1024, 0, stream>>>(deg, ptr, bsum);
    scan2_k<<<1, 64, 0, stream>>>(bsum, nsb);
    scan3_k<<<nsb, 1024, 0, stream>>>(ptr, cursor, bsum);
    scatter_k<<<(NE + 255) / 256, 256, 0, stream>>>(ei, dinv, cursor, crow, cw);

    // ---- layer 0 ----
    bnsplit_k<<<2048, 256, 0, stream>>>(x, DIN / 4, coef, 0, Xh, Xl);
    run_layer(Xh, Xl, DIN, W0, b0, out, tmpAB, tmpC, Wth, Wtl, ptr, crow, cw, stream);
    bn_stats1_k<<<BN_NBLK, 384, 0, stream>>>(out, partial);
    bn_finalize_k<<<1, 384, 0, stream>>>(partial, bn_gamma, bn_beta, coef);

    // ---- layer 1 ----
    bnsplit_k<<<2048, 256, 0, stream>>>(out, DCAT / 4, coef, 1, Xh, Xl);
    run_layer(Xh, Xl, DCAT, W1, b1, Hws, tmpAB, tmpC, Wth, Wtl, ptr, crow, cw, stream);
    bn_stats1_k<<<BN_NBLK, 384, 0, stream>>>(Hws, partial);
    bn_finalize_k<<<1, 384, 0, stream>>>(partial, bn_gamma + DCAT, bn_beta + DCAT, coef);

    // ---- layer 2 ----
    bnsplit_k<<<2048, 256, 0, stream>>>(Hws, DCAT / 4, coef, 1, Xh, Xl);
    run_layer(Xh, Xl, DCAT, W2, b2, out, tmpAB, tmpC, Wth, Wtl, ptr, crow, cw, stream);
}

// Round 5
// 1682.029 us; speedup vs baseline: 1.0776x; 1.0776x over previous
//
#include <hip/hip_runtime.h>
#include <hip/hip_bf16.h>

// ---------------- problem constants ----------------
#define NN 100000      // nodes
#define NE 800000      // edges
#define DIN 128
#define DCAT 384
#define BN_EPS 1e-5

typedef __attribute__((ext_vector_type(8))) short bf16x8;
typedef __attribute__((ext_vector_type(4))) float f32x4;
typedef __attribute__((ext_vector_type(4))) int   i32x4;

// ---------------- preprocessing kernels ----------------

__global__ void count_deg_k(const int* __restrict__ ei, int* __restrict__ deg) {
    int i = blockIdx.x * blockDim.x + threadIdx.x;
    if (i < NE) atomicAdd(&deg[ei[NE + i]], 1);   // col = ei[1][e]
}

__global__ void dinv_k(const int* __restrict__ deg, float* __restrict__ dinv) {
    int i = blockIdx.x * blockDim.x + threadIdx.x;
    if (i < NN) {
        int d = deg[i];
        dinv[i] = (d > 0) ? rsqrtf((float)d) : 0.f;
    }
}

__global__ void scan1_k(const int* __restrict__ deg, int* __restrict__ out,
                        int* __restrict__ bsum) {
    __shared__ int s[1024];
    int i = blockIdx.x * 1024 + threadIdx.x;
    int v = (i < NN) ? deg[i] : 0;
    s[threadIdx.x] = v;
    __syncthreads();
    for (int off = 1; off < 1024; off <<= 1) {
        int t = (threadIdx.x >= off) ? s[threadIdx.x - off] : 0;
        __syncthreads();
        s[threadIdx.x] += t;
        __syncthreads();
    }
    if (i < NN) out[i] = s[threadIdx.x] - v;   // exclusive
    if (threadIdx.x == 1023) bsum[blockIdx.x] = s[1023];
}

__global__ void scan2_k(int* __restrict__ bsum, int nb) {
    if (threadIdx.x == 0) {
        int acc = 0;
        for (int b = 0; b < nb; ++b) { int v = bsum[b]; bsum[b] = acc; acc += v; }
    }
}

__global__ void scan3_k(int* __restrict__ ptr, int* __restrict__ cursor,
                        const int* __restrict__ bsum) {
    int i = blockIdx.x * 1024 + threadIdx.x;
    if (i < NN) {
        int p = ptr[i] + bsum[blockIdx.x];
        ptr[i] = p;
        cursor[i] = p;
    }
    if (i == NN) ptr[NN] = NE;
}

// pack (row, weight) per edge into one int2
__global__ void scatter_k(const int* __restrict__ ei, const float* __restrict__ dinv,
                          int* __restrict__ cursor, int2* __restrict__ epack) {
    int i = blockIdx.x * blockDim.x + threadIdx.x;
    if (i >= NE) return;
    int r = ei[i];
    int c = ei[NE + i];
    int p = atomicAdd(&cursor[c], 1);
    float w = dinv[r] * dinv[c];
    epack[p] = make_int2(r, __builtin_bit_cast(int, w));
}

// ---------------- split-bf16 helpers ----------------

__device__ inline void split_trunc(float x, short& hi, short& lo) {
    unsigned u = __builtin_bit_cast(unsigned, x);
    hi = (short)(u >> 16);
    float hf = __builtin_bit_cast(float, u & 0xFFFF0000u);
    __hip_bfloat16 l = __float2bfloat16(x - hf);
    lo = *reinterpret_cast<short*>(&l);
}

// pre-split + transpose weights:  W (3,K,128) -> Wt_hi/lo (3,128,384) [group][col][k]
__global__ void wsplit_k(const float* __restrict__ W, int K,
                         short* __restrict__ Wth, short* __restrict__ Wtl) {
    int i = blockIdx.x * 256 + threadIdx.x;
    if (i >= 3 * K * 128) return;
    int c = i & 127;
    int k = (i >> 7) % K;
    int j = i / (K * 128);
    short h, l;
    split_trunc(W[i], h, l);
    size_t o = (size_t)j * 128 * 384 + (size_t)c * 384 + k;
    Wth[o] = h;
    Wtl[o] = l;
}

// ---------------- BN(optional)+ReLU + split X into bf16 hi/lo ----------------
__global__ __launch_bounds__(256) void bnsplit_k(
    const float* __restrict__ H, int Kc4,   // Kc4 = K/4
    const float2* __restrict__ coef, int use_bn,
    short* __restrict__ Xh, short* __restrict__ Xl) {
    size_t n4 = (size_t)NN * Kc4;
    for (size_t i = (size_t)blockIdx.x * blockDim.x + threadIdx.x; i < n4;
         i += (size_t)gridDim.x * blockDim.x) {
        float4 v = ((const float4*)H)[i];
        if (use_bn) {
            int c4 = (int)(i % Kc4) * 4;
            float2 c0 = coef[c4 + 0], c1 = coef[c4 + 1];
            float2 c2 = coef[c4 + 2], c3 = coef[c4 + 3];
            v.x = fmaxf(v.x * c0.x + c0.y, 0.f);
            v.y = fmaxf(v.y * c1.x + c1.y, 0.f);
            v.z = fmaxf(v.z * c2.x + c2.y, 0.f);
            v.w = fmaxf(v.w * c3.x + c3.y, 0.f);
        }
        short h0, l0, h1, l1, h2, l2, h3, l3;
        split_trunc(v.x, h0, l0);
        split_trunc(v.y, h1, l1);
        split_trunc(v.z, h2, l2);
        split_trunc(v.w, h3, l3);
        ((short4*)Xh)[i] = make_short4(h0, h1, h2, h3);
        ((short4*)Xl)[i] = make_short4(l0, l1, l2, l3);
    }
}

// ---------------- split-bf16 MFMA GEMM (R2 structure, bf16 inputs) ----------------
// 2D grid: x = row tile (A stream, consecutive blocks share B), y = group j.
// A and B tiles both LDS-staged per 32-K-step, 2 barriers, no swizzle.
#define GPITCH 40

__global__ __launch_bounds__(256, 4) void gemm3s_k(
    const short* __restrict__ Xh, const short* __restrict__ Xl, int K,
    const short* __restrict__ Wth, const short* __restrict__ Wtl,
    const float* __restrict__ bias,
    float* __restrict__ o0, int p0,
    float* __restrict__ o1, int p1,
    float* __restrict__ o2, int p2) {
    __shared__ short Ah[128 * GPITCH];
    __shared__ short Al[128 * GPITCH];
    __shared__ short Bh[128 * GPITCH];
    __shared__ short Bl[128 * GPITCH];

    const int j  = blockIdx.y;
    const int m0 = blockIdx.x * 128;

    const int t    = threadIdx.x;
    const int lane = t & 63;
    const int wv   = t >> 6;
    const int wr   = (wv >> 1) * 64;
    const int wc   = (wv & 1) * 64;
    const int lr   = lane & 15;
    const int lk   = lane >> 4;

    const short* Wh = Wth + (size_t)j * 128 * 384;
    const short* Wl = Wtl + (size_t)j * 128 * 384;

    // staging: thread covers row/col = t>>1, 16 shorts at kc=(t&1)*16
    const int srow = t >> 1;
    const int skc  = (t & 1) * 16;
    int gr = m0 + srow;
    if (gr >= NN) gr = NN - 1;
    const short* pAh = Xh + (size_t)gr * K + skc;
    const short* pAl = Xl + (size_t)gr * K + skc;
    const short* pBh = Wh + (size_t)srow * 384 + skc;
    const short* pBl = Wl + (size_t)srow * 384 + skc;
    const int soff = srow * GPITCH + skc;

    f32x4 acc[4][4];
#pragma unroll
    for (int a = 0; a < 4; ++a)
#pragma unroll
        for (int b = 0; b < 4; ++b) acc[a][b] = (f32x4){0.f, 0.f, 0.f, 0.f};

    for (int kb = 0; kb < K; kb += 32) {
        // issue global loads early (overlap prior MFMA)
        i32x4 a0 = *(const i32x4*)(pAh + kb);
        i32x4 a1 = *(const i32x4*)(pAh + kb + 8);
        i32x4 a2 = *(const i32x4*)(pAl + kb);
        i32x4 a3 = *(const i32x4*)(pAl + kb + 8);
        i32x4 b0 = *(const i32x4*)(pBh + kb);
        i32x4 b1 = *(const i32x4*)(pBh + kb + 8);
        i32x4 b2 = *(const i32x4*)(pBl + kb);
        i32x4 b3 = *(const i32x4*)(pBl + kb + 8);

        __syncthreads();   // prior frag reads complete before overwrite
        *(i32x4*)&Ah[soff]     = a0;
        *(i32x4*)&Ah[soff + 8] = a1;
        *(i32x4*)&Al[soff]     = a2;
        *(i32x4*)&Al[soff + 8] = a3;
        *(i32x4*)&Bh[soff]     = b0;
        *(i32x4*)&Bh[soff + 8] = b1;
        *(i32x4*)&Bl[soff]     = b2;
        *(i32x4*)&Bl[soff + 8] = b3;
        __syncthreads();

        bf16x8 ah[4], al[4];
#pragma unroll
        for (int mr = 0; mr < 4; ++mr) {
            const int rr = (wr + mr * 16 + lr) * GPITCH + lk * 8;
            ah[mr] = *(const bf16x8*)&Ah[rr];
            al[mr] = *(const bf16x8*)&Al[rr];
        }
#pragma unroll
        for (int nc = 0; nc < 4; ++nc) {
            const int cc = (wc + nc * 16 + lr) * GPITCH + lk * 8;
            bf16x8 bh = *(const bf16x8*)&Bh[cc];
            bf16x8 bl = *(const bf16x8*)&Bl[cc];
#pragma unroll
            for (int mr = 0; mr < 4; ++mr) {
                f32x4 a = acc[mr][nc];
                a = __builtin_amdgcn_mfma_f32_16x16x32_bf16(al[mr], bh, a, 0, 0, 0);
                a = __builtin_amdgcn_mfma_f32_16x16x32_bf16(ah[mr], bl, a, 0, 0, 0);
                a = __builtin_amdgcn_mfma_f32_16x16x32_bf16(ah[mr], bh, a, 0, 0, 0);
                acc[mr][nc] = a;
            }
        }
    }

    float* dst;
    int pitch;
    if (j == 0)      { dst = o0; pitch = p0; }
    else if (j == 1) { dst = o1; pitch = p1; }
    else             { dst = o2; pitch = p2; }

#pragma unroll
    for (int nc = 0; nc < 4; ++nc) {
        int col = wc + nc * 16 + lr;
        float bv = bias[j * 128 + col];
#pragma unroll
        for (int mr = 0; mr < 4; ++mr) {
            f32x4 a = acc[mr][nc];
#pragma unroll
            for (int rr = 0; rr < 4; ++rr) {
                int row = m0 + wr + mr * 16 + lk * 4 + rr;
                if (row < NN) dst[(size_t)row * pitch + col] = a[rr] + bv;
            }
        }
    }
}

// ---------------- fused dual SpMM over interleaved [T1|T2] (pitch 256) ----------------
// Per edge one 1024B row; unroll 4 -> 4 gathers in flight per wave.
__global__ __launch_bounds__(256) void spmm2_k(
    const int* __restrict__ ptr, const int2* __restrict__ ep,
    const float* __restrict__ inAB,     // pitch 256
    float* __restrict__ outA,           // H + 128 (pitch 384)
    float* __restrict__ outB) {         // tmpC (pitch 128)
    int wid  = (blockIdx.x * blockDim.x + threadIdx.x) >> 6;
    int lane = threadIdx.x & 63;
    if (wid >= NN) return;
    int e0 = ptr[wid], e1 = ptr[wid + 1];
    float4 acc = make_float4(0.f, 0.f, 0.f, 0.f);
    int e = e0;
    for (; e + 4 <= e1; e += 4) {
        int2 q0 = ep[e], q1 = ep[e + 1], q2 = ep[e + 2], q3 = ep[e + 3];
        float4 v0 = ((const float4*)(inAB + (size_t)q0.x * 256))[lane];
        float4 v1 = ((const float4*)(inAB + (size_t)q1.x * 256))[lane];
        float4 v2 = ((const float4*)(inAB + (size_t)q2.x * 256))[lane];
        float4 v3 = ((const float4*)(inAB + (size_t)q3.x * 256))[lane];
        float w0 = __builtin_bit_cast(float, q0.y);
        float w1 = __builtin_bit_cast(float, q1.y);
        float w2 = __builtin_bit_cast(float, q2.y);
        float w3 = __builtin_bit_cast(float, q3.y);
        acc.x += w0 * v0.x + w1 * v1.x + w2 * v2.x + w3 * v3.x;
        acc.y += w0 * v0.y + w1 * v1.y + w2 * v2.y + w3 * v3.y;
        acc.z += w0 * v0.z + w1 * v1.z + w2 * v2.z + w3 * v3.z;
        acc.w += w0 * v0.w + w1 * v1.w + w2 * v2.w + w3 * v3.w;
    }
    for (; e < e1; ++e) {
        int2 q0 = ep[e];
        float w0 = __builtin_bit_cast(float, q0.y);
        float4 v0 = ((const float4*)(inAB + (size_t)q0.x * 256))[lane];
        acc.x += w0 * v0.x;
        acc.y += w0 * v0.y;
        acc.z += w0 * v0.z;
        acc.w += w0 * v0.w;
    }
    if (lane < 32) ((float4*)(outA + (size_t)wid * 384))[lane] = acc;
    else           ((float4*)(outB + (size_t)wid * 128))[lane - 32] = acc;
}

// ---------------- single SpMM: 2 edges per wave (32 lanes each), unroll 8 ----------------
__global__ __launch_bounds__(256) void spmm_k(
    const int* __restrict__ ptr, const int2* __restrict__ ep,
    const float* __restrict__ xin,      // pitch 128
    float* __restrict__ xout, int pout) {
    int wid  = (blockIdx.x * blockDim.x + threadIdx.x) >> 6;
    int lane = threadIdx.x & 63;
    if (wid >= NN) return;
    int e0 = ptr[wid], e1 = ptr[wid + 1];
    int half = lane >> 5;
    int cl   = lane & 31;
    float4 acc = make_float4(0.f, 0.f, 0.f, 0.f);
    int e = e0;
    for (; e + 8 <= e1; e += 8) {
        int2 q0 = ep[e + half],     q1 = ep[e + 2 + half];
        int2 q2 = ep[e + 4 + half], q3 = ep[e + 6 + half];
        float4 v0 = ((const float4*)(xin + (size_t)q0.x * 128))[cl];
        float4 v1 = ((const float4*)(xin + (size_t)q1.x * 128))[cl];
        float4 v2 = ((const float4*)(xin + (size_t)q2.x * 128))[cl];
        float4 v3 = ((const float4*)(xin + (size_t)q3.x * 128))[cl];
        float w0 = __builtin_bit_cast(float, q0.y);
        float w1 = __builtin_bit_cast(float, q1.y);
        float w2 = __builtin_bit_cast(float, q2.y);
        float w3 = __builtin_bit_cast(float, q3.y);
        acc.x += w0 * v0.x + w1 * v1.x + w2 * v2.x + w3 * v3.x;
        acc.y += w0 * v0.y + w1 * v1.y + w2 * v2.y + w3 * v3.y;
        acc.z += w0 * v0.z + w1 * v1.z + w2 * v2.z + w3 * v3.z;
        acc.w += w0 * v0.w + w1 * v1.w + w2 * v2.w + w3 * v3.w;
    }
    for (; e + 2 <= e1; e += 2) {
        int2 q0 = ep[e + half];
        float w0 = __builtin_bit_cast(float, q0.y);
        float4 v0 = ((const float4*)(xin + (size_t)q0.x * 128))[cl];
        acc.x += w0 * v0.x;
        acc.y += w0 * v0.y;
        acc.z += w0 * v0.z;
        acc.w += w0 * v0.w;
    }
    if (e < e1 && half == 0) {
        int2 q0 = ep[e];
        float w0 = __builtin_bit_cast(float, q0.y);
        float4 v0 = ((const float4*)(xin + (size_t)q0.x * 128))[cl];
        acc.x += w0 * v0.x;
        acc.y += w0 * v0.y;
        acc.z += w0 * v0.z;
        acc.w += w0 * v0.w;
    }
    float4 o;
    o.x = acc.x + __shfl_xor(acc.x, 32);
    o.y = acc.y + __shfl_xor(acc.y, 32);
    o.z = acc.z + __shfl_xor(acc.z, 32);
    o.w = acc.w + __shfl_xor(acc.w, 32);
    if (half == 0) ((float4*)(xout + (size_t)wid * pout))[cl] = o;
}

// ---------------- BatchNorm stats ----------------
#define BN_ROWS 256
#define BN_NBLK ((NN + BN_ROWS - 1) / BN_ROWS)   // 391

__global__ void bn_stats1_k(const float* __restrict__ H, float* __restrict__ partial) {
    int c  = threadIdx.x;                 // 384 threads
    int r0 = blockIdx.x * BN_ROWS;
    int r1 = min(r0 + BN_ROWS, NN);
    float s = 0.f, s2 = 0.f;
    for (int r = r0; r < r1; ++r) {
        float v = H[(size_t)r * DCAT + c];
        s  += v;
        s2 += v * v;
    }
    partial[blockIdx.x * 768 + c]       = s;
    partial[blockIdx.x * 768 + 384 + c] = s2;
}

__global__ void bn_finalize_k(const float* __restrict__ partial,
                              const float* __restrict__ g, const float* __restrict__ b,
                              float2* __restrict__ coef) {
    int c = threadIdx.x;                  // 384 threads
    double s = 0.0, s2 = 0.0;
    for (int i = 0; i < BN_NBLK; ++i) {
        s  += (double)partial[i * 768 + c];
        s2 += (double)partial[i * 768 + 384 + c];
    }
    double mu  = s / (double)NN;
    double var = s2 / (double)NN - mu * mu;
    double inv = 1.0 / sqrt(var + (double)BN_EPS);
    float scale = (float)((double)g[c] * inv);
    float shift = (float)((double)b[c] - mu * (double)g[c] * inv);
    coef[c] = make_float2(scale, shift);
}

// ---------------- host-side orchestration ----------------

static void run_layer(const short* Xh, const short* Xl, int K,
                      const float* W, const float* bias,
                      float* Hout, float* tmpAB, float* tmpC,
                      short* Wth, short* Wtl,
                      const int* ptr, const int2* ep,
                      hipStream_t stream) {
    int nw = 3 * K * 128;
    wsplit_k<<<(nw + 255) / 256, 256, 0, stream>>>(W, K, Wth, Wtl);
    dim3 g((NN + 127) / 128, 3);
    gemm3s_k<<<g, 256, 0, stream>>>(Xh, Xl, K, Wth, Wtl, bias,
                                    Hout, DCAT, tmpAB, 256, tmpAB + 128, 256);
    int sg = (NN * 64 + 255) / 256;
    spmm2_k<<<sg, 256, 0, stream>>>(ptr, ep, tmpAB, Hout + 128, tmpC);
    spmm_k<<<sg, 256, 0, stream>>>(ptr, ep, tmpC, Hout + 256, DCAT);
}

extern "C" void kernel_launch(void* const* d_in, const int* in_sizes, int n_in,
                              void* d_out, int out_size, void* d_ws, size_t ws_size,
                              hipStream_t stream) {
    const float* x        = (const float*)d_in[0];
    const int*   ei       = (const int*)d_in[1];
    const float* W0       = (const float*)d_in[2];
    const float* b0       = (const float*)d_in[3];
    const float* W1       = (const float*)d_in[4];
    const float* b1       = (const float*)d_in[5];
    const float* W2       = (const float*)d_in[6];
    const float* b2       = (const float*)d_in[7];
    const float* bn_gamma = (const float*)d_in[8];
    const float* bn_beta  = (const float*)d_in[9];
    float* out = (float*)d_out;

    // workspace carve-up (512B aligned slabs)
    char* p = (char*)d_ws;
    auto alloc = [&](size_t bytes) -> void* {
        void* r = (void*)p;
        p += (bytes + 511) & ~(size_t)511;
        return r;
    };
    short* Xh      = (short*)alloc((size_t)NN * DCAT * 2);   // 76.8 MB
    short* Xl      = (short*)alloc((size_t)NN * DCAT * 2);   // 76.8 MB
    float* tmpAB   = (float*)alloc((size_t)NN * 256 * 4);    // 102.4 MB
    float* Hws     = (float*)alloc((size_t)NN * DCAT * 4);   // 153.6 MB
    int*   deg     = (int*)alloc((size_t)NN * 4);
    float* dinv    = (float*)alloc((size_t)NN * 4);
    int*   ptr     = (int*)alloc((size_t)(NN + 1) * 4);
    int*   cursor  = (int*)alloc((size_t)NN * 4);
    int*   bsum    = (int*)alloc(1024);
    int2*  epack   = (int2*)alloc((size_t)NE * 8);
    float* partial = (float*)alloc((size_t)BN_NBLK * 768 * 4);
    float2* coef   = (float2*)alloc(384 * 8);
    short* Wth     = (short*)alloc((size_t)3 * 128 * 384 * 2);
    short* Wtl     = (short*)alloc((size_t)3 * 128 * 384 * 2);
    // tmpC (N x 128 fp32, 51.2 MB) aliases Xh (dead after the layer's gemm).
    float* tmpC = (float*)Xh;

    // ---- graph preprocessing ----
    hipMemsetAsync(deg, 0, (size_t)NN * 4, stream);
    count_deg_k<<<(NE + 255) / 256, 256, 0, stream>>>(ei, deg);
    dinv_k<<<(NN + 255) / 256, 256, 0, stream>>>(deg, dinv);
    int nsb = (NN + 1023) / 1024;   // 98
    scan1_k<<<nsb, 1024, 0, stream>>>(deg, ptr, bsum);
    scan2_k<<<1, 64, 0, stream>>>(bsum, nsb);
    scan3_k<<<nsb, 1024, 0, stream>>>(ptr, cursor, bsum);
    scatter_k<<<(NE + 255) / 256, 256, 0, stream>>>(ei, dinv, cursor, epack);

    // ---- layer 0 ----
    bnsplit_k<<<2048, 256, 0, stream>>>(x, DIN / 4, coef, 0, Xh, Xl);
    run_layer(Xh, Xl, DIN, W0, b0, out, tmpAB, tmpC, Wth, Wtl, ptr, epack, stream);
    bn_stats1_k<<<BN_NBLK, 384, 0, stream>>>(out, partial);
    bn_finalize_k<<<1, 384, 0, stream>>>(partial, bn_gamma, bn_beta, coef);

    // ---- layer 1 ----
    bnsplit_k<<<2048, 256, 0, stream>>>(out, DCAT / 4, coef, 1, Xh, Xl);
    run_layer(Xh, Xl, DCAT, W1, b1, Hws, tmpAB, tmpC, Wth, Wtl, ptr, epack, stream);
    bn_stats1_k<<<BN_NBLK, 384, 0, stream>>>(Hws, partial);
    bn_finalize_k<<<1, 384, 0, stream>>>(partial, bn_gamma + DCAT, bn_beta + DCAT, coef);

    // ---- layer 2 ----
    bnsplit_k<<<2048, 256, 0, stream>>>(Hws, DCAT / 4, coef, 1, Xh, Xl);
    run_layer(Xh, Xl, DCAT, W2, b2, out, tmpAB, tmpC, Wth, Wtl, ptr, epack, stream);
}

// Round 6
// 1621.015 us; speedup vs baseline: 1.1182x; 1.0376x over previous
//
#include <hip/hip_runtime.h>
#include <hip/hip_bf16.h>
#include <hip/hip_fp16.h>

// ---------------- problem constants ----------------
#define NN 100000      // nodes
#define NE 800000      // edges
#define DIN 128
#define DCAT 384
#define BN_EPS 1e-5

typedef __attribute__((ext_vector_type(8))) short bf16x8;
typedef __attribute__((ext_vector_type(4))) float f32x4;
typedef __attribute__((ext_vector_type(4))) int   i32x4;

// ---------------- preprocessing kernels ----------------

__global__ void count_deg_k(const int* __restrict__ ei, int* __restrict__ deg) {
    int i = blockIdx.x * blockDim.x + threadIdx.x;
    if (i < NE) atomicAdd(&deg[ei[NE + i]], 1);   // col = ei[1][e]
}

__global__ void dinv_k(const int* __restrict__ deg, float* __restrict__ dinv) {
    int i = blockIdx.x * blockDim.x + threadIdx.x;
    if (i < NN) {
        int d = deg[i];
        dinv[i] = (d > 0) ? rsqrtf((float)d) : 0.f;
    }
}

__global__ void scan1_k(const int* __restrict__ deg, int* __restrict__ out,
                        int* __restrict__ bsum) {
    __shared__ int s[1024];
    int i = blockIdx.x * 1024 + threadIdx.x;
    int v = (i < NN) ? deg[i] : 0;
    s[threadIdx.x] = v;
    __syncthreads();
    for (int off = 1; off < 1024; off <<= 1) {
        int t = (threadIdx.x >= off) ? s[threadIdx.x - off] : 0;
        __syncthreads();
        s[threadIdx.x] += t;
        __syncthreads();
    }
    if (i < NN) out[i] = s[threadIdx.x] - v;   // exclusive
    if (threadIdx.x == 1023) bsum[blockIdx.x] = s[1023];
}

__global__ void scan2_k(int* __restrict__ bsum, int nb) {
    if (threadIdx.x == 0) {
        int acc = 0;
        for (int b = 0; b < nb; ++b) { int v = bsum[b]; bsum[b] = acc; acc += v; }
    }
}

__global__ void scan3_k(int* __restrict__ ptr, int* __restrict__ cursor,
                        const int* __restrict__ bsum) {
    int i = blockIdx.x * 1024 + threadIdx.x;
    if (i < NN) {
        int p = ptr[i] + bsum[blockIdx.x];
        ptr[i] = p;
        cursor[i] = p;
    }
    if (i == NN) ptr[NN] = NE;
}

// pack (row, weight) per edge into one int2
__global__ void scatter_k(const int* __restrict__ ei, const float* __restrict__ dinv,
                          int* __restrict__ cursor, int2* __restrict__ epack) {
    int i = blockIdx.x * blockDim.x + threadIdx.x;
    if (i >= NE) return;
    int r = ei[i];
    int c = ei[NE + i];
    int p = atomicAdd(&cursor[c], 1);
    float w = dinv[r] * dinv[c];
    epack[p] = make_int2(r, __builtin_bit_cast(int, w));
}

// ---------------- split-bf16 helpers ----------------

__device__ inline void split_trunc(float x, short& hi, short& lo) {
    unsigned u = __builtin_bit_cast(unsigned, x);
    hi = (short)(u >> 16);
    float hf = __builtin_bit_cast(float, u & 0xFFFF0000u);
    __hip_bfloat16 l = __float2bfloat16(x - hf);
    lo = *reinterpret_cast<short*>(&l);
}

// pre-split + transpose weights:  W (3,K,128) -> Wt_hi/lo (3,128,384) [group][col][k]
__global__ void wsplit_k(const float* __restrict__ W, int K,
                         short* __restrict__ Wth, short* __restrict__ Wtl) {
    int i = blockIdx.x * 256 + threadIdx.x;
    if (i >= 3 * K * 128) return;
    int c = i & 127;
    int k = (i >> 7) % K;
    int j = i / (K * 128);
    short h, l;
    split_trunc(W[i], h, l);
    size_t o = (size_t)j * 128 * 384 + (size_t)c * 384 + k;
    Wth[o] = h;
    Wtl[o] = l;
}

// ---------------- BN(optional)+ReLU + split X into bf16 hi/lo ----------------
__global__ __launch_bounds__(256) void bnsplit_k(
    const float* __restrict__ H, int Kc4,   // Kc4 = K/4
    const float2* __restrict__ coef, int use_bn,
    short* __restrict__ Xh, short* __restrict__ Xl) {
    size_t n4 = (size_t)NN * Kc4;
    for (size_t i = (size_t)blockIdx.x * blockDim.x + threadIdx.x; i < n4;
         i += (size_t)gridDim.x * blockDim.x) {
        float4 v = ((const float4*)H)[i];
        if (use_bn) {
            int c4 = (int)(i % Kc4) * 4;
            float2 c0 = coef[c4 + 0], c1 = coef[c4 + 1];
            float2 c2 = coef[c4 + 2], c3 = coef[c4 + 3];
            v.x = fmaxf(v.x * c0.x + c0.y, 0.f);
            v.y = fmaxf(v.y * c1.x + c1.y, 0.f);
            v.z = fmaxf(v.z * c2.x + c2.y, 0.f);
            v.w = fmaxf(v.w * c3.x + c3.y, 0.f);
        }
        short h0, l0, h1, l1, h2, l2, h3, l3;
        split_trunc(v.x, h0, l0);
        split_trunc(v.y, h1, l1);
        split_trunc(v.z, h2, l2);
        split_trunc(v.w, h3, l3);
        ((short4*)Xh)[i] = make_short4(h0, h1, h2, h3);
        ((short4*)Xl)[i] = make_short4(l0, l1, l2, l3);
    }
}

// ---------------- split-bf16 MFMA GEMM (R2/R5 structure, bf16 inputs) ----------------
// 2D grid: x = row tile, y = group j. A and B LDS-staged, 2 barriers per step.
// j=0 -> fp32 into H (pitch 384); j=1/2 -> fp16 interleaved into o12 (pitch 256).
#define GPITCH 40

__global__ __launch_bounds__(256, 4) void gemm3s_k(
    const short* __restrict__ Xh, const short* __restrict__ Xl, int K,
    const short* __restrict__ Wth, const short* __restrict__ Wtl,
    const float* __restrict__ bias,
    float* __restrict__ o0, __half* __restrict__ o12) {
    __shared__ short Ah[128 * GPITCH];
    __shared__ short Al[128 * GPITCH];
    __shared__ short Bh[128 * GPITCH];
    __shared__ short Bl[128 * GPITCH];

    const int j  = blockIdx.y;
    const int m0 = blockIdx.x * 128;

    const int t    = threadIdx.x;
    const int lane = t & 63;
    const int wv   = t >> 6;
    const int wr   = (wv >> 1) * 64;
    const int wc   = (wv & 1) * 64;
    const int lr   = lane & 15;
    const int lk   = lane >> 4;

    const short* Wh = Wth + (size_t)j * 128 * 384;
    const short* Wl = Wtl + (size_t)j * 128 * 384;

    const int srow = t >> 1;
    const int skc  = (t & 1) * 16;
    int gr = m0 + srow;
    if (gr >= NN) gr = NN - 1;
    const short* pAh = Xh + (size_t)gr * K + skc;
    const short* pAl = Xl + (size_t)gr * K + skc;
    const short* pBh = Wh + (size_t)srow * 384 + skc;
    const short* pBl = Wl + (size_t)srow * 384 + skc;
    const int soff = srow * GPITCH + skc;

    f32x4 acc[4][4];
#pragma unroll
    for (int a = 0; a < 4; ++a)
#pragma unroll
        for (int b = 0; b < 4; ++b) acc[a][b] = (f32x4){0.f, 0.f, 0.f, 0.f};

    for (int kb = 0; kb < K; kb += 32) {
        i32x4 a0 = *(const i32x4*)(pAh + kb);
        i32x4 a1 = *(const i32x4*)(pAh + kb + 8);
        i32x4 a2 = *(const i32x4*)(pAl + kb);
        i32x4 a3 = *(const i32x4*)(pAl + kb + 8);
        i32x4 b0 = *(const i32x4*)(pBh + kb);
        i32x4 b1 = *(const i32x4*)(pBh + kb + 8);
        i32x4 b2 = *(const i32x4*)(pBl + kb);
        i32x4 b3 = *(const i32x4*)(pBl + kb + 8);

        __syncthreads();
        *(i32x4*)&Ah[soff]     = a0;
        *(i32x4*)&Ah[soff + 8] = a1;
        *(i32x4*)&Al[soff]     = a2;
        *(i32x4*)&Al[soff + 8] = a3;
        *(i32x4*)&Bh[soff]     = b0;
        *(i32x4*)&Bh[soff + 8] = b1;
        *(i32x4*)&Bl[soff]     = b2;
        *(i32x4*)&Bl[soff + 8] = b3;
        __syncthreads();

        bf16x8 ah[4], al[4];
#pragma unroll
        for (int mr = 0; mr < 4; ++mr) {
            const int rr = (wr + mr * 16 + lr) * GPITCH + lk * 8;
            ah[mr] = *(const bf16x8*)&Ah[rr];
            al[mr] = *(const bf16x8*)&Al[rr];
        }
#pragma unroll
        for (int nc = 0; nc < 4; ++nc) {
            const int cc = (wc + nc * 16 + lr) * GPITCH + lk * 8;
            bf16x8 bh = *(const bf16x8*)&Bh[cc];
            bf16x8 bl = *(const bf16x8*)&Bl[cc];
#pragma unroll
            for (int mr = 0; mr < 4; ++mr) {
                f32x4 a = acc[mr][nc];
                a = __builtin_amdgcn_mfma_f32_16x16x32_bf16(al[mr], bh, a, 0, 0, 0);
                a = __builtin_amdgcn_mfma_f32_16x16x32_bf16(ah[mr], bl, a, 0, 0, 0);
                a = __builtin_amdgcn_mfma_f32_16x16x32_bf16(ah[mr], bh, a, 0, 0, 0);
                acc[mr][nc] = a;
            }
        }
    }

    if (j == 0) {
#pragma unroll
        for (int nc = 0; nc < 4; ++nc) {
            int col = wc + nc * 16 + lr;
            float bv = bias[col];
#pragma unroll
            for (int mr = 0; mr < 4; ++mr) {
                f32x4 a = acc[mr][nc];
#pragma unroll
                for (int rr = 0; rr < 4; ++rr) {
                    int row = m0 + wr + mr * 16 + lk * 4 + rr;
                    if (row < NN) o0[(size_t)row * DCAT + col] = a[rr] + bv;
                }
            }
        }
    } else {
        __half* dsth = o12 + (j == 2 ? 128 : 0);
#pragma unroll
        for (int nc = 0; nc < 4; ++nc) {
            int col = wc + nc * 16 + lr;
            float bv = bias[j * 128 + col];
#pragma unroll
            for (int mr = 0; mr < 4; ++mr) {
                f32x4 a = acc[mr][nc];
#pragma unroll
                for (int rr = 0; rr < 4; ++rr) {
                    int row = m0 + wr + mr * 16 + lk * 4 + rr;
                    if (row < NN)
                        dsth[(size_t)row * 256 + col] = __float2half(a[rr] + bv);
                }
            }
        }
    }
}

// ---------------- fused dual SpMM over interleaved fp16 [T1|T2] (pitch 256 halfs) ----
// Per edge one 512B gather (8B/lane). lanes 0-31 accumulate T1, 32-63 T2.
__global__ __launch_bounds__(256) void spmm2h_k(
    const int* __restrict__ ptr, const int2* __restrict__ ep,
    const __half* __restrict__ inAB,    // pitch 256 halfs
    float* __restrict__ outA,           // H + 128 (pitch 384, fp32)
    __half* __restrict__ outB) {        // tmpC (pitch 128 halfs)
    int wid  = (blockIdx.x * blockDim.x + threadIdx.x) >> 6;
    int lane = threadIdx.x & 63;
    if (wid >= NN) return;
    int e0 = ptr[wid], e1 = ptr[wid + 1];
    float4 acc = make_float4(0.f, 0.f, 0.f, 0.f);
    const uint2* base = (const uint2*)inAB;   // 64 uint2 per row
    int e = e0;
    for (; e + 4 <= e1; e += 4) {
        int2 q0 = ep[e], q1 = ep[e + 1], q2 = ep[e + 2], q3 = ep[e + 3];
        uint2 u0 = base[(size_t)q0.x * 64 + lane];
        uint2 u1 = base[(size_t)q1.x * 64 + lane];
        uint2 u2 = base[(size_t)q2.x * 64 + lane];
        uint2 u3 = base[(size_t)q3.x * 64 + lane];
        float w0 = __builtin_bit_cast(float, q0.y);
        float w1 = __builtin_bit_cast(float, q1.y);
        float w2 = __builtin_bit_cast(float, q2.y);
        float w3 = __builtin_bit_cast(float, q3.y);
        float2 a0 = __half22float2(__builtin_bit_cast(__half2, u0.x));
        float2 b0 = __half22float2(__builtin_bit_cast(__half2, u0.y));
        float2 a1 = __half22float2(__builtin_bit_cast(__half2, u1.x));
        float2 b1 = __half22float2(__builtin_bit_cast(__half2, u1.y));
        float2 a2 = __half22float2(__builtin_bit_cast(__half2, u2.x));
        float2 b2 = __half22float2(__builtin_bit_cast(__half2, u2.y));
        float2 a3 = __half22float2(__builtin_bit_cast(__half2, u3.x));
        float2 b3 = __half22float2(__builtin_bit_cast(__half2, u3.y));
        acc.x += w0 * a0.x + w1 * a1.x + w2 * a2.x + w3 * a3.x;
        acc.y += w0 * a0.y + w1 * a1.y + w2 * a2.y + w3 * a3.y;
        acc.z += w0 * b0.x + w1 * b1.x + w2 * b2.x + w3 * b3.x;
        acc.w += w0 * b0.y + w1 * b1.y + w2 * b2.y + w3 * b3.y;
    }
    for (; e < e1; ++e) {
        int2 q0 = ep[e];
        float w0 = __builtin_bit_cast(float, q0.y);
        uint2 u0 = base[(size_t)q0.x * 64 + lane];
        float2 a0 = __half22float2(__builtin_bit_cast(__half2, u0.x));
        float2 b0 = __half22float2(__builtin_bit_cast(__half2, u0.y));
        acc.x += w0 * a0.x;
        acc.y += w0 * a0.y;
        acc.z += w0 * b0.x;
        acc.w += w0 * b0.y;
    }
    if (lane < 32) {
        ((float4*)(outA + (size_t)wid * 384))[lane] = acc;
    } else {
        __half2 h0 = __float22half2_rn(make_float2(acc.x, acc.y));
        __half2 h1 = __float22half2_rn(make_float2(acc.z, acc.w));
        uint2 u = make_uint2(__builtin_bit_cast(unsigned, h0),
                             __builtin_bit_cast(unsigned, h1));
        ((uint2*)(outB + (size_t)wid * 128))[lane - 32] = u;
    }
}

// ---------------- hop-2 SpMM over fp16 rows (256B): 2 edges/wave, unroll 8 --------
__global__ __launch_bounds__(256) void spmmh_k(
    const int* __restrict__ ptr, const int2* __restrict__ ep,
    const __half* __restrict__ xin,     // pitch 128 halfs
    float* __restrict__ xout) {         // H + 256 (pitch 384, fp32)
    int wid  = (blockIdx.x * blockDim.x + threadIdx.x) >> 6;
    int lane = threadIdx.x & 63;
    if (wid >= NN) return;
    int e0 = ptr[wid], e1 = ptr[wid + 1];
    int hf = lane >> 5;
    int cl = lane & 31;
    float4 acc = make_float4(0.f, 0.f, 0.f, 0.f);
    const uint2* base = (const uint2*)xin;    // 32 uint2 per row
    int e = e0;
    for (; e + 8 <= e1; e += 8) {
        int2 q0 = ep[e + hf],     q1 = ep[e + 2 + hf];
        int2 q2 = ep[e + 4 + hf], q3 = ep[e + 6 + hf];
        uint2 u0 = base[(size_t)q0.x * 32 + cl];
        uint2 u1 = base[(size_t)q1.x * 32 + cl];
        uint2 u2 = base[(size_t)q2.x * 32 + cl];
        uint2 u3 = base[(size_t)q3.x * 32 + cl];
        float w0 = __builtin_bit_cast(float, q0.y);
        float w1 = __builtin_bit_cast(float, q1.y);
        float w2 = __builtin_bit_cast(float, q2.y);
        float w3 = __builtin_bit_cast(float, q3.y);
        float2 a0 = __half22float2(__builtin_bit_cast(__half2, u0.x));
        float2 b0 = __half22float2(__builtin_bit_cast(__half2, u0.y));
        float2 a1 = __half22float2(__builtin_bit_cast(__half2, u1.x));
        float2 b1 = __half22float2(__builtin_bit_cast(__half2, u1.y));
        float2 a2 = __half22float2(__builtin_bit_cast(__half2, u2.x));
        float2 b2 = __half22float2(__builtin_bit_cast(__half2, u2.y));
        float2 a3 = __half22float2(__builtin_bit_cast(__half2, u3.x));
        float2 b3 = __half22float2(__builtin_bit_cast(__half2, u3.y));
        acc.x += w0 * a0.x + w1 * a1.x + w2 * a2.x + w3 * a3.x;
        acc.y += w0 * a0.y + w1 * a1.y + w2 * a2.y + w3 * a3.y;
        acc.z += w0 * b0.x + w1 * b1.x + w2 * b2.x + w3 * b3.x;
        acc.w += w0 * b0.y + w1 * b1.y + w2 * b2.y + w3 * b3.y;
    }
    for (; e + 2 <= e1; e += 2) {
        int2 q0 = ep[e + hf];
        float w0 = __builtin_bit_cast(float, q0.y);
        uint2 u0 = base[(size_t)q0.x * 32 + cl];
        float2 a0 = __half22float2(__builtin_bit_cast(__half2, u0.x));
        float2 b0 = __half22float2(__builtin_bit_cast(__half2, u0.y));
        acc.x += w0 * a0.x;
        acc.y += w0 * a0.y;
        acc.z += w0 * b0.x;
        acc.w += w0 * b0.y;
    }
    if (e < e1 && hf == 0) {
        int2 q0 = ep[e];
        float w0 = __builtin_bit_cast(float, q0.y);
        uint2 u0 = base[(size_t)q0.x * 32 + cl];
        float2 a0 = __half22float2(__builtin_bit_cast(__half2, u0.x));
        float2 b0 = __half22float2(__builtin_bit_cast(__half2, u0.y));
        acc.x += w0 * a0.x;
        acc.y += w0 * a0.y;
        acc.z += w0 * b0.x;
        acc.w += w0 * b0.y;
    }
    float4 o;
    o.x = acc.x + __shfl_xor(acc.x, 32);
    o.y = acc.y + __shfl_xor(acc.y, 32);
    o.z = acc.z + __shfl_xor(acc.z, 32);
    o.w = acc.w + __shfl_xor(acc.w, 32);
    if (hf == 0) ((float4*)(xout + (size_t)wid * 384))[cl] = o;
}

// ---------------- BatchNorm stats ----------------
#define BN_ROWS 64
#define BN_NBLK ((NN + BN_ROWS - 1) / BN_ROWS)   // 1563

__global__ void bn_stats1_k(const float* __restrict__ H, float* __restrict__ partial) {
    int c  = threadIdx.x;                 // 384 threads
    int r0 = blockIdx.x * BN_ROWS;
    int r1 = min(r0 + BN_ROWS, NN);
    float s = 0.f, s2 = 0.f;
    for (int r = r0; r < r1; ++r) {
        float v = H[(size_t)r * DCAT + c];
        s  += v;
        s2 += v * v;
    }
    partial[blockIdx.x * 768 + c]       = s;
    partial[blockIdx.x * 768 + 384 + c] = s2;
}

__global__ void bn_finalize_k(const float* __restrict__ partial,
                              const float* __restrict__ g, const float* __restrict__ b,
                              float2* __restrict__ coef) {
    int c = threadIdx.x;                  // 384 threads
    double s = 0.0, s2 = 0.0;
    for (int i = 0; i < BN_NBLK; ++i) {
        s  += (double)partial[i * 768 + c];
        s2 += (double)partial[i * 768 + 384 + c];
    }
    double mu  = s / (double)NN;
    double var = s2 / (double)NN - mu * mu;
    double inv = 1.0 / sqrt(var + (double)BN_EPS);
    float scale = (float)((double)g[c] * inv);
    float shift = (float)((double)b[c] - mu * (double)g[c] * inv);
    coef[c] = make_float2(scale, shift);
}

// ---------------- host-side orchestration ----------------

static void run_layer(const short* Xh, const short* Xl, int K,
                      const float* W, const float* bias,
                      float* Hout, __half* tmpAB, __half* tmpC,
                      short* Wth, short* Wtl,
                      const int* ptr, const int2* ep,
                      hipStream_t stream) {
    int nw = 3 * K * 128;
    wsplit_k<<<(nw + 255) / 256, 256, 0, stream>>>(W, K, Wth, Wtl);
    dim3 g((NN + 127) / 128, 3);
    gemm3s_k<<<g, 256, 0, stream>>>(Xh, Xl, K, Wth, Wtl, bias, Hout, tmpAB);
    int sg = (NN * 64 + 255) / 256;
    spmm2h_k<<<sg, 256, 0, stream>>>(ptr, ep, tmpAB, Hout + 128, tmpC);
    spmmh_k<<<sg, 256, 0, stream>>>(ptr, ep, tmpC, Hout + 256);
}

extern "C" void kernel_launch(void* const* d_in, const int* in_sizes, int n_in,
                              void* d_out, int out_size, void* d_ws, size_t ws_size,
                              hipStream_t stream) {
    const float* x        = (const float*)d_in[0];
    const int*   ei       = (const int*)d_in[1];
    const float* W0       = (const float*)d_in[2];
    const float* b0       = (const float*)d_in[3];
    const float* W1       = (const float*)d_in[4];
    const float* b1       = (const float*)d_in[5];
    const float* W2       = (const float*)d_in[6];
    const float* b2       = (const float*)d_in[7];
    const float* bn_gamma = (const float*)d_in[8];
    const float* bn_beta  = (const float*)d_in[9];
    float* out = (float*)d_out;

    // workspace carve-up (512B aligned slabs)
    char* p = (char*)d_ws;
    auto alloc = [&](size_t bytes) -> void* {
        void* r = (void*)p;
        p += (bytes + 511) & ~(size_t)511;
        return r;
    };
    short*  Xh      = (short*)alloc((size_t)NN * DCAT * 2);   // 76.8 MB
    short*  Xl      = (short*)alloc((size_t)NN * DCAT * 2);   // 76.8 MB
    __half* tmpAB   = (__half*)alloc((size_t)NN * 256 * 2);   // 51.2 MB
    float*  Hws     = (float*)alloc((size_t)NN * DCAT * 4);   // 153.6 MB
    int*    deg     = (int*)alloc((size_t)NN * 4);
    float*  dinv    = (float*)alloc((size_t)NN * 4);
    int*    ptr     = (int*)alloc((size_t)(NN + 1) * 4);
    int*    cursor  = (int*)alloc((size_t)NN * 4);
    int*    bsum    = (int*)alloc(1024);
    int2*   epack   = (int2*)alloc((size_t)NE * 8);
    float*  partial = (float*)alloc((size_t)BN_NBLK * 768 * 4);
    float2* coef    = (float2*)alloc(384 * 8);
    short*  Wth     = (short*)alloc((size_t)3 * 128 * 384 * 2);
    short*  Wtl     = (short*)alloc((size_t)3 * 128 * 384 * 2);
    // tmpC (N x 128 fp16, 25.6 MB) aliases Xh (dead after the layer's gemm).
    __half* tmpC = (__half*)Xh;

    // ---- graph preprocessing ----
    hipMemsetAsync(deg, 0, (size_t)NN * 4, stream);
    count_deg_k<<<(NE + 255) / 256, 256, 0, stream>>>(ei, deg);
    dinv_k<<<(NN + 255) / 256, 256, 0, stream>>>(deg, dinv);
    int nsb = (NN + 1023) / 1024;   // 98
    scan1_k<<<nsb, 1024, 0, stream>>>(deg, ptr, bsum);
    scan2_k<<<1, 64, 0, stream>>>(bsum, nsb);
    scan3_k<<<nsb, 1024, 0, stream>>>(ptr, cursor, bsum);
    scatter_k<<<(NE + 255) / 256, 256, 0, stream>>>(ei, dinv, cursor, epack);

    // ---- layer 0 ----
    bnsplit_k<<<2048, 256, 0, stream>>>(x, DIN / 4, coef, 0, Xh, Xl);
    run_layer(Xh, Xl, DIN, W0, b0, out, tmpAB, tmpC, Wth, Wtl, ptr, epack, stream);
    bn_stats1_k<<<BN_NBLK, 384, 0, stream>>>(out, partial);
    bn_finalize_k<<<1, 384, 0, stream>>>(partial, bn_gamma, bn_beta, coef);

    // ---- layer 1 ----
    bnsplit_k<<<2048, 256, 0, stream>>>(out, DCAT / 4, coef, 1, Xh, Xl);
    run_layer(Xh, Xl, DCAT, W1, b1, Hws, tmpAB, tmpC, Wth, Wtl, ptr, epack, stream);
    bn_stats1_k<<<BN_NBLK, 384, 0, stream>>>(Hws, partial);
    bn_finalize_k<<<1, 384, 0, stream>>>(partial, bn_gamma + DCAT, bn_beta + DCAT, coef);

    // ---- layer 2 ----
    bnsplit_k<<<2048, 256, 0, stream>>>(Hws, DCAT / 4, coef, 1, Xh, Xl);
    run_layer(Xh, Xl, DCAT, W2, b2, out, tmpAB, tmpC, Wth, Wtl, ptr, epack, stream);
}